// Round 20
// baseline (60.720 us; speedup 1.0000x reference)
//
#include <hip/hip_runtime.h>
#include <hip/hip_bf16.h>

#define NUM_OPS 8
#define D 1024
#define B_ROWS 8192

typedef unsigned short ushort_t;
typedef __attribute__((ext_vector_type(8))) short bf16x8;
typedef __attribute__((ext_vector_type(4))) float f32x4;
typedef __attribute__((ext_vector_type(4))) float float4v;
typedef __attribute__((ext_vector_type(8))) unsigned short ushort8;

__device__ __forceinline__ unsigned short f2bf(float f) {
    union { float f; unsigned int u; } v; v.f = f;
    unsigned int u = v.u;
    unsigned int lsb = (u >> 16) & 1u;
    u += 0x7fffu + lsb;   // round-to-nearest-even
    return (unsigned short)(u >> 16);
}

__device__ __forceinline__ void load_lds16(const void* g, void* l) {
    __builtin_amdgcn_global_load_lds(
        (const __attribute__((address_space(1))) void*)g,
        (__attribute__((address_space(3))) void*)l,
        16, 0, 0);
}

// deterministic top-2 (matches jax top_k tie-breaking: earliest index wins)
__device__ __forceinline__ void top2(const float* __restrict__ logits, int& i0, int& i1) {
    float best = -__builtin_inff(); i0 = 0;
    for (int i = 0; i < NUM_OPS; ++i) { float v = logits[i]; if (v > best) { best = v; i0 = i; } }
    float best2 = -__builtin_inff(); i1 = 0;
    for (int i = 0; i < NUM_OPS; ++i) {
        if (i == i0) continue;
        float v = logits[i]; if (v > best2) { best2 = v; i1 = i; }
    }
}

// -------- merged prep: x->bf16 linear (blocks 0..4095), W gather-transpose --
__global__ void prep_kernel(const float* __restrict__ x,
                            const float* __restrict__ Ws,
                            const float* __restrict__ logits,
                            ushort_t* __restrict__ xbf,
                            ushort_t* __restrict__ Wt) {
    __shared__ float t[32][33];
    const int bid = blockIdx.x;
    const int tid = threadIdx.x;
    if (bid < 4096) {
        // convert_x (r9-verified)
        int i = (bid * 256 + tid) * 8;
        float4v v0 = *(const float4v*)(x + i);
        float4v v1 = *(const float4v*)(x + i + 4);
        ushort8 o;
        o[0] = f2bf(v0[0]); o[1] = f2bf(v0[1]); o[2] = f2bf(v0[2]); o[3] = f2bf(v0[3]);
        o[4] = f2bf(v1[0]); o[5] = f2bf(v1[1]); o[6] = f2bf(v1[2]); o[7] = f2bf(v1[3]);
        *(ushort8*)(xbf + i) = o;
    } else {
        // gather_transpose_W (r9-verified): Wt[e][n*D+k] = bf16(W_sel[k*D+n])
        int i0, i1; top2(logits, i0, i1);
        const int b  = bid - 4096;
        const int e    = b >> 10;
        const int tile = b & 1023;
        const int td = (tile >> 5) << 5;
        const int te = (tile & 31) << 5;
        const int tx = tid & 31, ty = tid >> 5;
        const float* W = Ws + (size_t)(e ? i1 : i0) * D * D;
        for (int r = 0; r < 4; ++r)
            t[ty + 8 * r][tx] = W[(size_t)(td + ty + 8 * r) * D + te + tx];
        __syncthreads();
        ushort_t* o = Wt + (size_t)e * D * D;
        for (int r = 0; r < 4; ++r)
            o[(size_t)(te + ty + 8 * r) * D + td + tx] = f2bf(t[tx][ty + 8 * r]);
    }
}

// -------- staging (r9-verified pattern): linear LDS dest, inv-swizzled src --
// LDS row = 128B; byte (r*128+c') holds global col-byte (c' ^ ((r&7)<<4)).
__device__ __forceinline__ void stageA2(const ushort_t* __restrict__ xbf, int brow,
                                        int u, ushort_t* dst, int tid) {
    #pragma unroll
    for (int q = 0; q < 4; ++q) {                       // 256 rows x 128B = 32KB
        const int c   = q * 512 + tid;
        const int rr  = c >> 3;
        const int gcb = ((c & 7) * 16) ^ ((rr & 7) << 4);
        load_lds16(xbf + (size_t)(brow + rr) * D + u * 64 + (gcb >> 1), dst + c * 8);
    }
}
// B tile: rows = e*128 + n (256 rows x 128B = 32KB), same swizzle
__device__ __forceinline__ void stageB2(const ushort_t* __restrict__ Wt, int bcol,
                                        int u, ushort_t* dst, int tid) {
    #pragma unroll
    for (int q = 0; q < 4; ++q) {
        const int c   = q * 512 + tid;
        const int rr  = c >> 3;
        const int e   = rr >> 7, n = rr & 127;
        const int gcb = ((c & 7) * 16) ^ ((rr & 7) << 4);
        load_lds16(Wt + (size_t)e * D * D + (size_t)(bcol + n) * D + u * 64 + (gcb >> 1),
                   dst + c * 8);
    }
}

#define SB()    __builtin_amdgcn_sched_barrier(0)
#define PRIO1() __builtin_amdgcn_s_setprio(1)
#define PRIO0() __builtin_amdgcn_s_setprio(0)
#define VMW(N)  do { asm volatile("s_waitcnt vmcnt(" #N ")" ::: "memory"); SB(); } while (0)
#define BAR()   do { __builtin_amdgcn_s_barrier(); SB(); } while (0)

// -------- fused dual-expert GEMM: 256r x 128c x 2e, high-intensity 2-phase --
// 8 waves (2r x 4c). Wave: 128r x 32c x 2e -> acc[2][8][2] = 128 VGPR,
// 87 FLOP per LDS-read byte (vs 65 in r19) -- block-tile port traffic
// 256KB per 16.8M FLOP (vs 176KB/8.4M): 28% less port time per FLOP.
// Classic dbuf 2-phase (one barrier/tile, stage issued top-of-tile, WAR-safe
// by the barrier); cross-wave read/MFMA stagger (m114) provides the overlap.
__global__ __launch_bounds__(512, 2)
void gemm_dual(const ushort_t* __restrict__ xbf, const ushort_t* __restrict__ Wt,
               const float* __restrict__ bs, const float* __restrict__ logits,
               float* __restrict__ out) {
    __shared__ __align__(16) ushort_t As[2][256 * 64];   // 2 x 32KB
    __shared__ __align__(16) ushort_t Bs[2][256 * 64];   // 2 x 32KB

    const int tid  = threadIdx.x;
    const int wv   = tid >> 6;
    const int lane = tid & 63;
    const int rgrp = wv >> 2;          // 0..1  (128-row halves)
    const int cgrp = wv & 3;           // 0..3  (32-col groups)
    const int l15  = lane & 15, lq = lane >> 4;
    const int swz  = (l15 & 7) << 4;
    const int x0   = (lq * 16) ^ swz;
    const int x1   = (64 + lq * 16) ^ swz;

    const int bid  = blockIdx.x;       // grid 256 = 32 row-panels x 8 col-panels
    const int brow = (bid & 31) * 256;
    const int bcol = (bid >> 5) * 128;

    f32x4 acc[2][8][2] = {};

    // prologue: stage tile 0
    stageA2(xbf, brow, 0, As[0], tid);
    stageB2(Wt,  bcol, 0, Bs[0], tid);

    #pragma unroll 1
    for (int u = 0; u < 16; ++u) {
        VMW(0);                         // stage(u) landed (issued last tile)
        BAR();                          // slot[u&1] visible; old reads done
        if (u < 15) {                   // stage(u+1) -> other slot (WAR-safe)
            stageA2(xbf, brow, u + 1, As[(u + 1) & 1], tid);
            stageB2(Wt,  bcol, u + 1, Bs[(u + 1) & 1], tid);
        }
        const char* cA = (const char*)As[u & 1];
        const char* cB = (const char*)Bs[u & 1];

        bf16x8 a[2][8], b[2][2][2];
        #pragma unroll
        for (int kk = 0; kk < 2; ++kk)
            #pragma unroll
            for (int m = 0; m < 8; ++m)
                a[kk][m] = *(const bf16x8*)(cA +
                    (size_t)((rgrp * 128 + m * 16 + l15) * 128) + (kk ? x1 : x0));
        #pragma unroll
        for (int e = 0; e < 2; ++e)
            #pragma unroll
            for (int kk = 0; kk < 2; ++kk)
                #pragma unroll
                for (int n16 = 0; n16 < 2; ++n16)
                    b[e][kk][n16] = *(const bf16x8*)(cB +
                        (size_t)((e * 128 + cgrp * 32 + n16 * 16 + l15) * 128) +
                        (kk ? x1 : x0));

        PRIO1();
        #pragma unroll
        for (int kk = 0; kk < 2; ++kk)
            #pragma unroll
            for (int e = 0; e < 2; ++e)
                #pragma unroll
                for (int m = 0; m < 8; ++m)
                    #pragma unroll
                    for (int n16 = 0; n16 < 2; ++n16)
                        acc[e][m][n16] = __builtin_amdgcn_mfma_f32_16x16x32_bf16(
                            a[kk][m], b[e][kk][n16], acc[e][m][n16], 0, 0, 0);
        PRIO0();
    }

    // ---- epilogue: per-expert bias + relu, sum, store f32
    int i0, i1; top2(logits, i0, i1);
    #pragma unroll
    for (int n16 = 0; n16 < 2; ++n16) {
        const int col = bcol + cgrp * 32 + n16 * 16 + l15;
        const float bb0 = bs[i0 * D + col];
        const float bb1 = bs[i1 * D + col];
        #pragma unroll
        for (int m = 0; m < 8; ++m) {
            const int rbase = brow + rgrp * 128 + m * 16 + lq * 4;
            #pragma unroll
            for (int i = 0; i < 4; ++i) {
                float v0 = acc[0][m][n16][i] + bb0; v0 = v0 > 0.f ? v0 : 0.f;
                float v1 = acc[1][m][n16][i] + bb1; v1 = v1 > 0.f ? v1 : 0.f;
                out[(size_t)(rbase + i) * D + col] = v0 + v1;
            }
        }
    }
}

extern "C" void kernel_launch(void* const* d_in, const int* in_sizes, int n_in,
                              void* d_out, int out_size, void* d_ws, size_t ws_size,
                              hipStream_t stream) {
    const float* x      = (const float*)d_in[0];
    const float* logits = (const float*)d_in[1];
    const float* Ws     = (const float*)d_in[2];
    const float* bs     = (const float*)d_in[3];
    float* out = (float*)d_out;

    char* ws = (char*)d_ws;
    ushort_t* xbf = (ushort_t*)ws;                                   // 16 MB
    ushort_t* Wt  = (ushort_t*)(ws + (size_t)B_ROWS * D * 2);        //  4 MB

    prep_kernel<<<4096 + 2048, 256, 0, stream>>>(x, Ws, logits, xbf, Wt);
    gemm_dual<<<256, 512, 0, stream>>>(xbf, Wt, bs, logits, out);
}

// Round 21
// 46.900 us; speedup vs baseline: 1.2947x; 1.2947x over previous
//
#include <hip/hip_runtime.h>
#include <hip/hip_bf16.h>

#define NUM_OPS 8
#define D 1024
#define B_ROWS 8192

typedef unsigned short ushort_t;
typedef __attribute__((ext_vector_type(8))) short bf16x8;
typedef __attribute__((ext_vector_type(4))) float f32x4;
typedef __attribute__((ext_vector_type(4))) float float4v;
typedef __attribute__((ext_vector_type(8))) unsigned short ushort8;

__device__ __forceinline__ unsigned short f2bf(float f) {
    union { float f; unsigned int u; } v; v.f = f;
    unsigned int u = v.u;
    unsigned int lsb = (u >> 16) & 1u;
    u += 0x7fffu + lsb;   // round-to-nearest-even
    return (unsigned short)(u >> 16);
}

__device__ __forceinline__ void load_lds16(const void* g, void* l) {
    __builtin_amdgcn_global_load_lds(
        (const __attribute__((address_space(1))) void*)g,
        (__attribute__((address_space(3))) void*)l,
        16, 0, 0);
}

// deterministic top-2 (matches jax top_k tie-breaking: earliest index wins)
__device__ __forceinline__ void top2(const float* __restrict__ logits, int& i0, int& i1) {
    float best = -__builtin_inff(); i0 = 0;
    for (int i = 0; i < NUM_OPS; ++i) { float v = logits[i]; if (v > best) { best = v; i0 = i; } }
    float best2 = -__builtin_inff(); i1 = 0;
    for (int i = 0; i < NUM_OPS; ++i) {
        if (i == i0) continue;
        float v = logits[i]; if (v > best2) { best2 = v; i1 = i; }
    }
}

// -------- merged prep: x->bf16 linear (blocks 0..4095), W gather-transpose --
__global__ void prep_kernel(const float* __restrict__ x,
                            const float* __restrict__ Ws,
                            const float* __restrict__ logits,
                            ushort_t* __restrict__ xbf,
                            ushort_t* __restrict__ Wt) {
    __shared__ float t[32][33];
    const int bid = blockIdx.x;
    const int tid = threadIdx.x;
    if (bid < 4096) {
        // convert_x (r9-verified)
        int i = (bid * 256 + tid) * 8;
        float4v v0 = *(const float4v*)(x + i);
        float4v v1 = *(const float4v*)(x + i + 4);
        ushort8 o;
        o[0] = f2bf(v0[0]); o[1] = f2bf(v0[1]); o[2] = f2bf(v0[2]); o[3] = f2bf(v0[3]);
        o[4] = f2bf(v1[0]); o[5] = f2bf(v1[1]); o[6] = f2bf(v1[2]); o[7] = f2bf(v1[3]);
        *(ushort8*)(xbf + i) = o;
    } else {
        // gather_transpose_W (r9-verified): Wt[e][n*D+k] = bf16(W_sel[k*D+n])
        int i0, i1; top2(logits, i0, i1);
        const int b  = bid - 4096;
        const int e    = b >> 10;
        const int tile = b & 1023;
        const int td = (tile >> 5) << 5;
        const int te = (tile & 31) << 5;
        const int tx = tid & 31, ty = tid >> 5;
        const float* W = Ws + (size_t)(e ? i1 : i0) * D * D;
        for (int r = 0; r < 4; ++r)
            t[ty + 8 * r][tx] = W[(size_t)(td + ty + 8 * r) * D + te + tx];
        __syncthreads();
        ushort_t* o = Wt + (size_t)e * D * D;
        for (int r = 0; r < 4; ++r)
            o[(size_t)(te + ty + 8 * r) * D + td + tx] = f2bf(t[tx][ty + 8 * r]);
    }
}

// -------- staging (r9-verified): linear LDS dest, inverse-swizzled source ---
// LDS row = 128B; byte (r*128+c') holds global col-byte (c' ^ ((r&7)<<4)).
__device__ __forceinline__ void stageA(const ushort_t* __restrict__ xbf, int brow,
                                       int u, ushort_t* dst, int tid) {
    #pragma unroll
    for (int q = 0; q < 4; ++q) {                       // 256 rows x 128B = 32KB
        const int c   = q * 512 + tid;
        const int rr  = c >> 3;
        const int gcb = ((c & 7) * 16) ^ ((rr & 7) << 4);
        load_lds16(xbf + (size_t)(brow + rr) * D + u * 64 + (gcb >> 1), dst + c * 8);
    }
}
__device__ __forceinline__ void stageB(const ushort_t* __restrict__ Wt, int bcol,
                                       int u, ushort_t* dst, int tid) {
    #pragma unroll
    for (int q = 0; q < 2; ++q) {                       // 2e x 64 rows x 128B = 16KB
        const int c   = q * 512 + tid;
        const int e   = c >> 9, cc = c & 511;
        const int n   = cc >> 3;
        const int gcb = ((cc & 7) * 16) ^ ((n & 7) << 4);
        load_lds16(Wt + (size_t)e * D * D + (size_t)(bcol + n) * D + u * 64 + (gcb >> 1),
                   dst + c * 8);
    }
}

#define SB()    __builtin_amdgcn_sched_barrier(0)
#define PRIO1() __builtin_amdgcn_s_setprio(1)
#define PRIO0() __builtin_amdgcn_s_setprio(0)
#define VMW(N)  do { asm volatile("s_waitcnt vmcnt(" #N ")" ::: "memory"); SB(); } while (0)
#define LGW(N)  do { asm volatile("s_waitcnt lgkmcnt(" #N ")" ::: "memory"); SB(); } while (0)
#define BAR()   do { __builtin_amdgcn_s_barrier(); SB(); } while (0)

// inline-asm LDS read: allocator cannot collapse these; regs stay live.
#define DSR(dst, addr, imm)                                                    \
    asm volatile("ds_read_b128 %0, %1 offset:" #imm : "=v"(dst) : "v"(addr))

// issue one tile's 16 fragment ds_reads into named set P from slots SA/SBB.
#define ISSUE_DS(P, SA, SBB)                                                   \
    do {                                                                       \
        unsigned aA0 = (unsigned)(size_t)(SA) + aro + x0;                      \
        unsigned aA1 = (unsigned)(size_t)(SA) + aro + x1;                      \
        unsigned aB0 = (unsigned)(size_t)(SBB) + bro + x0;                     \
        unsigned aB1 = (unsigned)(size_t)(SBB) + bro + x1;                     \
        DSR(P##a0, aA0, 0);    DSR(P##a1, aA0, 2048);                          \
        DSR(P##a2, aA0, 4096); DSR(P##a3, aA0, 6144);                          \
        DSR(P##a4, aA1, 0);    DSR(P##a5, aA1, 2048);                          \
        DSR(P##a6, aA1, 4096); DSR(P##a7, aA1, 6144);                          \
        DSR(P##b0, aB0, 0);    DSR(P##b1, aB0, 2048);                          \
        DSR(P##b4, aB0, 8192); DSR(P##b5, aB0, 10240);                         \
        DSR(P##b2, aB1, 0);    DSR(P##b3, aB1, 2048);                          \
        DSR(P##b6, aB1, 8192); DSR(P##b7, aB1, 10240);                         \
    } while (0)

#define MF(a, b, c) __builtin_amdgcn_mfma_f32_16x16x32_bf16(a, b, c, 0, 0, 0)
#define Q(P, A, B, E, M, N) acc[E][M][N] = MF(P##A, P##B, acc[E][M][N])

// 32 MFMA on set P. a index = kk*4+m ; b index = e*4 + kk*2 + n16 (r8-verified)
#define MFMA_SET(P)                                                            \
    do {                                                                       \
        PRIO1();                                                               \
        Q(P,a0,b0,0,0,0); Q(P,a0,b1,0,0,1); Q(P,a0,b4,1,0,0); Q(P,a0,b5,1,0,1);\
        Q(P,a1,b0,0,1,0); Q(P,a1,b1,0,1,1); Q(P,a1,b4,1,1,0); Q(P,a1,b5,1,1,1);\
        Q(P,a2,b0,0,2,0); Q(P,a2,b1,0,2,1); Q(P,a2,b4,1,2,0); Q(P,a2,b5,1,2,1);\
        Q(P,a3,b0,0,3,0); Q(P,a3,b1,0,3,1); Q(P,a3,b4,1,3,0); Q(P,a3,b5,1,3,1);\
        Q(P,a4,b2,0,0,0); Q(P,a4,b3,0,0,1); Q(P,a4,b6,1,0,0); Q(P,a4,b7,1,0,1);\
        Q(P,a5,b2,0,1,0); Q(P,a5,b3,0,1,1); Q(P,a5,b6,1,1,0); Q(P,a5,b7,1,1,1);\
        Q(P,a6,b2,0,2,0); Q(P,a6,b3,0,2,1); Q(P,a6,b6,1,2,0); Q(P,a6,b7,1,2,1);\
        Q(P,a7,b2,0,3,0); Q(P,a7,b3,0,3,1); Q(P,a7,b6,1,3,0); Q(P,a7,b7,1,3,1);\
        PRIO0();                                                               \
    } while (0)

// one K-tile u (steady state), deep-staged:
//   VMW(6): drains stage(u+1) (issued TWO tiles ago -> free); stage(u+2)'s
//     6 loads stay in flight -- staging never drains to zero (Little's law).
//   BARRIER: slot[(u+1)%3] visible to all waves.
//   ISSUE_DS F(u+1) (16 asm ds_read; fly under MFMA(u))
//   LGW(15): drains F(u)'s 16 reads (issued last tile) -> slot[u%3]'s old
//     content is dead for ALL consumers of this tile.
//   stage(u+3) into slot[(u+3)%3] == slot[u%3] -- WAR-safe (see r18/r19).
//   MFMA_SET(F(u))
#define TILE(SETN, SA, SBB, SU, DA, DB, SETC, DOSTG, VN)                       \
    do {                                                                       \
        VMW(VN);                                                               \
        BAR();                                                                 \
        ISSUE_DS(SETN, SA, SBB);                                               \
        SB();                                                                  \
        LGW(15);                                                               \
        if (DOSTG) { stageA(xbf, brow, (SU), DA, tid);                         \
                     stageB(Wt,  bcol, (SU), DB, tid); }                       \
        SB();                                                                  \
        MFMA_SET(SETC);                                                        \
        SB();                                                                  \
    } while (0)

// -------- fused dual-expert GEMM: asm LDS pipeline + never-drained staging --
// Session-best structure (r19, 47.19us total): asm-forced ds_read pipeline
// (LDS-read overlaps MFMA) + 3-tile-deep counted staging (in-flight never
// drains to zero).
__global__ __launch_bounds__(512, 2)
void gemm_dual(const ushort_t* __restrict__ xbf, const ushort_t* __restrict__ Wt,
               const float* __restrict__ bs, const float* __restrict__ logits,
               float* __restrict__ out) {
    __shared__ __align__(16) ushort_t As0[256 * 64], As1[256 * 64], As2[256 * 64];
    __shared__ __align__(16) ushort_t Bs0[2 * 64 * 64], Bs1[2 * 64 * 64], Bs2[2 * 64 * 64];

    const int tid  = threadIdx.x;
    const int wv   = tid >> 6;
    const int lane = tid & 63;
    const int rgrp = wv >> 1, cgrp = wv & 1;
    const int l15  = lane & 15, lq = lane >> 4;
    const int swz  = (l15 & 7) << 4;
    const int x0   = (lq * 16) ^ swz;
    const int x1   = (64 + lq * 16) ^ swz;
    const unsigned aro = (unsigned)((rgrp * 64 + l15) * 128);
    const unsigned bro = (unsigned)((cgrp * 32 + l15) * 128);

    const int bid  = blockIdx.x;
    const int brow = (bid & 31) * 256;
    const int bcol = (bid >> 5) * 64;

    f32x4 acc[2][4][2] = {};

    bf16x8 Xa0, Xa1, Xa2, Xa3, Xa4, Xa5, Xa6, Xa7;
    bf16x8 Xb0, Xb1, Xb2, Xb3, Xb4, Xb5, Xb6, Xb7;
    bf16x8 Ya0, Ya1, Ya2, Ya3, Ya4, Ya5, Ya6, Ya7;
    bf16x8 Yb0, Yb1, Yb2, Yb3, Yb4, Yb5, Yb6, Yb7;

    // prologue: stage tiles 0,1,2 (18 loads); wait stage(0) only (12 stay in
    // flight); issue F(0) reads into X.
    stageA(xbf, brow, 0, As0, tid); stageB(Wt, bcol, 0, Bs0, tid);
    stageA(xbf, brow, 1, As1, tid); stageB(Wt, bcol, 1, Bs1, tid);
    stageA(xbf, brow, 2, As2, tid); stageB(Wt, bcol, 2, Bs2, tid);
    SB();
    VMW(12);
    BAR();
    ISSUE_DS(X, As0, Bs0);
    SB();

    //    next-set rd-slot    stage-u  dst      cur  stg  vmn
    TILE(Y, As1, Bs1,  3, As0, Bs0, X, true,  6);   // u=0
    TILE(X, As2, Bs2,  4, As1, Bs1, Y, true,  6);   // u=1
    TILE(Y, As0, Bs0,  5, As2, Bs2, X, true,  6);   // u=2
    TILE(X, As1, Bs1,  6, As0, Bs0, Y, true,  6);   // u=3
    TILE(Y, As2, Bs2,  7, As1, Bs1, X, true,  6);   // u=4
    TILE(X, As0, Bs0,  8, As2, Bs2, Y, true,  6);   // u=5
    TILE(Y, As1, Bs1,  9, As0, Bs0, X, true,  6);   // u=6
    TILE(X, As2, Bs2, 10, As1, Bs1, Y, true,  6);   // u=7
    TILE(Y, As0, Bs0, 11, As2, Bs2, X, true,  6);   // u=8
    TILE(X, As1, Bs1, 12, As0, Bs0, Y, true,  6);   // u=9
    TILE(Y, As2, Bs2, 13, As1, Bs1, X, true,  6);   // u=10
    TILE(X, As0, Bs0, 14, As2, Bs2, Y, true,  6);   // u=11
    TILE(Y, As1, Bs1, 15, As0, Bs0, X, true,  6);   // u=12
    TILE(X, As2, Bs2,  0, As0, Bs0, Y, false, 6);   // u=13 (no stage)
    TILE(Y, As0, Bs0,  0, As0, Bs0, X, false, 0);   // u=14 (drain stage(15))
    // u=15: drain Y's reads, compute.
    LGW(0);
    MFMA_SET(Y);
    SB();

    // ---- epilogue: per-expert bias + relu, sum, store f32 (r9-verified)
    int i0, i1; top2(logits, i0, i1);
    #pragma unroll
    for (int n16 = 0; n16 < 2; ++n16) {
        const int col = bcol + cgrp * 32 + n16 * 16 + l15;
        const float bb0 = bs[i0 * D + col];
        const float bb1 = bs[i1 * D + col];
        #pragma unroll
        for (int m = 0; m < 4; ++m) {
            const int rbase = brow + rgrp * 64 + m * 16 + lq * 4;
            #pragma unroll
            for (int i = 0; i < 4; ++i) {
                float v0 = acc[0][m][n16][i] + bb0; v0 = v0 > 0.f ? v0 : 0.f;
                float v1 = acc[1][m][n16][i] + bb1; v1 = v1 > 0.f ? v1 : 0.f;
                out[(size_t)(rbase + i) * D + col] = v0 + v1;
            }
        }
    }
}

extern "C" void kernel_launch(void* const* d_in, const int* in_sizes, int n_in,
                              void* d_out, int out_size, void* d_ws, size_t ws_size,
                              hipStream_t stream) {
    const float* x      = (const float*)d_in[0];
    const float* logits = (const float*)d_in[1];
    const float* Ws     = (const float*)d_in[2];
    const float* bs     = (const float*)d_in[3];
    float* out = (float*)d_out;

    char* ws = (char*)d_ws;
    ushort_t* xbf = (ushort_t*)ws;                                   // 16 MB
    ushort_t* Wt  = (ushort_t*)(ws + (size_t)B_ROWS * D * 2);        //  4 MB

    prep_kernel<<<4096 + 2048, 256, 0, stream>>>(x, Ws, logits, xbf, Wt);
    gemm_dual<<<512, 512, 0, stream>>>(xbf, Wt, bs, logits, out);
}